// Round 3
// baseline (3333.228 us; speedup 1.0000x reference)
//
#include <hip/hip_runtime.h>
#include <hip/hip_bf16.h>

typedef __bf16 bf16;
typedef __bf16 bf16x4 __attribute__((ext_vector_type(4)));
typedef __bf16 bf16x8 __attribute__((ext_vector_type(8)));
typedef float  f32x4  __attribute__((ext_vector_type(4)));

#define TT    128
#define BB    1024
#define VOCAB 128
#define EE    256
#define HH    1024
#define NTAGS 8
#define KTOT  (EE + HH)   // 1280
#define NKT   (KTOT / 64) // 20 K-tiles of 64
#define HKT0  (EE / 64)   // first K-tile that stages hprev (=4)

// ---------------------------------------------------------------- fp32 -> bf16
__global__ __launch_bounds__(256) void cvt_k(const float* __restrict__ s,
                                             bf16* __restrict__ d, int n) {
    int i = (blockIdx.x * 256 + threadIdx.x) * 4;
    if (i >= n) return;
    float4 v = *(const float4*)(s + i);
    bf16x4 o = {(bf16)v.x, (bf16)v.y, (bf16)v.z, (bf16)v.w};
    *(bf16x4*)(d + i) = o;
}

// ---------------------------------------------------------------- seq lengths
__global__ __launch_bounds__(256) void seqlen_k(const int* __restrict__ ids,
                                                int* __restrict__ sl) {
    int b = blockIdx.x * 256 + threadIdx.x;   // grid 4 -> 1024 rows
    int c = 0;
    for (int t = 0; t < TT; ++t) c += (ids[b * TT + t] != 0) ? 1 : 0;
    sl[b] = c;
}

// ---------------------------------------------------------------- RNN step
// Tile: BM=64 (batch) x BN=128 (hidden), BK=64, K = [emb(256) | h(1024)].
// 4 waves, each 32x64 (2 M-sub x 4 N-sub of 16x16x32 MFMA).
// Folded logits: every block stages ALL of hprev through sA (K-tiles 4..19),
// so N-block x computes tag x's logits for step t-1 (no atomics).
__global__ __launch_bounds__(256)
void rnn_step(const int*   __restrict__ ids,
              const bf16*  __restrict__ emb,    // bf16 ws copy
              const bf16*  __restrict__ W_ih,   // bf16 ws copy
              const bf16*  __restrict__ W_hh,   // bf16 ws copy
              const float* __restrict__ b_ih,
              const float* __restrict__ b_hh,
              const float* __restrict__ W_out,  // fp32 original
              const float* __restrict__ b_out,
              const int*   __restrict__ seqlen,
              const bf16*  __restrict__ hprev,
              bf16*        __restrict__ hnext,
              float*       __restrict__ out,
              int t)
{
    __shared__ __align__(16) bf16  sA[64 * 72];    //  9216 B
    __shared__ __align__(16) bf16  sB[128 * 72];   // 18432 B
    __shared__ __align__(16) float sW[HH];         //  4096 B fp32 W_out row

    const int tid   = threadIdx.x;
    const int tag   = blockIdx.x;          // N-tile index == tag (8 each)
    const int Nbase = blockIdx.x * 128;
    const int Mbase = blockIdx.y * 64;
    const int wave  = tid >> 6, lane = tid & 63;
    const int quad  = lane >> 4, l15 = lane & 15;
    const int wMoff = (wave >> 1) * 32, wNoff = (wave & 1) * 64;

    *(float4*)(sW + tid * 4) = *(const float4*)(W_out + tag * HH + tid * 4);

    f32x4 acc[2][4];
#pragma unroll
    for (int a = 0; a < 2; ++a)
#pragma unroll
        for (int b = 0; b < 4; ++b) {
            f32x4 z = {0.f, 0.f, 0.f, 0.f};
            acc[a][b] = z;
        }

    const int lb  = tid >> 2;    // logit row 0..63
    const int ltp = tid & 3;     // logit col-quarter
    float ls = 0.f;

    for (int kt = 0; kt < NKT; ++kt) {
        const int kbase = kt * 64;
        __syncthreads();
        if (kt < HKT0) {
#pragma unroll
            for (int it = 0; it < 2; ++it) {
                int c = tid + it * 256, r = c >> 3, co = (c & 7) * 8;
                int id = ids[(Mbase + r) * TT + t];       // emb row 0 is zeros
                *(int4*)(sA + r * 72 + co) =
                    *(const int4*)(emb + id * EE + kbase + co);
            }
#pragma unroll
            for (int it = 0; it < 4; ++it) {
                int c = tid + it * 256, rn = c >> 3, co = (c & 7) * 8;
                *(int4*)(sB + rn * 72 + co) =
                    *(const int4*)(W_ih + (Nbase + rn) * EE + kbase + co);
            }
        } else {
            const int kh = kbase - EE;
#pragma unroll
            for (int it = 0; it < 2; ++it) {
                int c = tid + it * 256, r = c >> 3, co = (c & 7) * 8;
                *(int4*)(sA + r * 72 + co) =
                    *(const int4*)(hprev + (Mbase + r) * HH + kh + co);
            }
#pragma unroll
            for (int it = 0; it < 4; ++it) {
                int c = tid + it * 256, rn = c >> 3, co = (c & 7) * 8;
                *(int4*)(sB + rn * 72 + co) =
                    *(const int4*)(W_hh + (Nbase + rn) * HH + kh + co);
            }
        }
        __syncthreads();
#pragma unroll
        for (int kk = 0; kk < 64; kk += 32) {
            bf16x8 af[2], bfr[4];
#pragma unroll
            for (int sm = 0; sm < 2; ++sm)
                af[sm] = *(const bf16x8*)(sA + (wMoff + sm * 16 + l15) * 72 + kk + quad * 8);
#pragma unroll
            for (int sn = 0; sn < 4; ++sn)
                bfr[sn] = *(const bf16x8*)(sB + (wNoff + sn * 16 + l15) * 72 + kk + quad * 8);
#pragma unroll
            for (int sm = 0; sm < 2; ++sm)
#pragma unroll
                for (int sn = 0; sn < 4; ++sn)
                    acc[sm][sn] = __builtin_amdgcn_mfma_f32_16x16x32_bf16(
                        af[sm], bfr[sn], acc[sm][sn], 0, 0, 0);
        }
        // folded logits of step t-1 from the staged hprev slab
        if (t > 0 && kt >= HKT0) {
            const int hc = kbase - EE;
            const bf16*  hrow = sA + lb * 72 + ltp * 16;
            const float* wrow = sW + hc + ltp * 16;
            bf16x8 hv0 = *(const bf16x8*)(hrow);
            bf16x8 hv1 = *(const bf16x8*)(hrow + 8);
#pragma unroll
            for (int j = 0; j < 8; ++j) ls += (float)hv0[j] * wrow[j];
#pragma unroll
            for (int j = 0; j < 8; ++j) ls += (float)hv1[j] * wrow[8 + j];
        }
    }

    if (t > 0) {
        ls += __shfl_xor(ls, 1);
        ls += __shfl_xor(ls, 2);
        if (ltp == 0)
            out[(Mbase + lb) * (TT * NTAGS) + (t - 1) * NTAGS + tag] =
                ls + b_out[tag];
    }

#pragma unroll
    for (int sm = 0; sm < 2; ++sm)
#pragma unroll
        for (int sn = 0; sn < 4; ++sn)
#pragma unroll
            for (int r = 0; r < 4; ++r) {
                int b_loc = wMoff + sm * 16 + quad * 4 + r;   // M = batch
                int b_g   = Mbase + b_loc;
                int n_loc = wNoff + sn * 16 + l15;            // N = hidden
                int i     = Nbase + n_loc;
                float pre = acc[sm][sn][r] + b_ih[i] + b_hh[i];
                float nh  = tanhf(pre);
                hnext[b_g * HH + i] =
                    (t < seqlen[b_g]) ? (bf16)nh : hprev[b_g * HH + i];
            }
}

// ---------------------------------------------------------------- tail logits (t = 127)
__global__ __launch_bounds__(256) void tail_logits(const bf16*  __restrict__ h,
                                                   const float* __restrict__ W_out,
                                                   const float* __restrict__ b_out,
                                                   float* __restrict__ out) {
    const int tag   = blockIdx.x;          // 0..7
    const int Mbase = blockIdx.y * 64;     // 0..15
    const int lb = threadIdx.x >> 2, sub = threadIdx.x & 3;
    const bf16*  hr = h + (Mbase + lb) * HH + sub * 256;
    const float* wr = W_out + tag * HH + sub * 256;
    float s = 0.f;
    for (int c8 = 0; c8 < 256; c8 += 8) {
        bf16x8 hv = *(const bf16x8*)(hr + c8);
#pragma unroll
        for (int j = 0; j < 8; ++j) s += (float)hv[j] * wr[c8 + j];
    }
    s += __shfl_xor(s, 1);
    s += __shfl_xor(s, 2);
    if (sub == 0)
        out[(Mbase + lb) * (TT * NTAGS) + 127 * NTAGS + tag] = s + b_out[tag];
}

// ---------------------------------------------------------------- launch
extern "C" void kernel_launch(void* const* d_in, const int* in_sizes, int n_in,
                              void* d_out, int out_size, void* d_ws, size_t ws_size,
                              hipStream_t stream) {
    const int*   ids   = (const int*)d_in[0];
    const float* emb   = (const float*)d_in[1];
    const float* W_ih  = (const float*)d_in[2];
    const float* W_hh  = (const float*)d_in[3];
    const float* b_ih  = (const float*)d_in[4];
    const float* b_hh  = (const float*)d_in[5];
    const float* W_out = (const float*)d_in[6];
    const float* b_out = (const float*)d_in[7];
    float* out = (float*)d_out;

    // ws layout (6.57 MB total): sl | emb16 | Wih16 | Whh16 | h0 | h1
    char* ws = (char*)d_ws;
    size_t off = 0;
    int*  sl    = (int*)(ws + off);  off += 4096;
    bf16* emb16 = (bf16*)(ws + off); off += (size_t)VOCAB * EE * sizeof(bf16);
    bf16* Wih16 = (bf16*)(ws + off); off += (size_t)HH * EE * sizeof(bf16);
    bf16* Whh16 = (bf16*)(ws + off); off += (size_t)HH * HH * sizeof(bf16);
    bf16* h0    = (bf16*)(ws + off); off += (size_t)BB * HH * sizeof(bf16);
    bf16* h1    = (bf16*)(ws + off); off += (size_t)BB * HH * sizeof(bf16);

    if (ws_size < off) return;  // diagnostic: leaves out==0 (err=max|ref|), not NaN

    cvt_k<<<(VOCAB * EE / 4 + 255) / 256, 256, 0, stream>>>(emb, emb16, VOCAB * EE);
    cvt_k<<<(HH * EE / 4 + 255) / 256, 256, 0, stream>>>(W_ih, Wih16, HH * EE);
    cvt_k<<<(HH * HH / 4 + 255) / 256, 256, 0, stream>>>(W_hh, Whh16, HH * HH);
    hipMemsetAsync(h0, 0, (size_t)BB * HH * sizeof(bf16), stream);
    seqlen_k<<<4, 256, 0, stream>>>(ids, sl);

    bf16* hb[2] = {h0, h1};
    for (int t = 0; t < TT; ++t)
        rnn_step<<<dim3(8, 16), 256, 0, stream>>>(
            ids, emb16, Wih16, Whh16, b_ih, b_hh, W_out, b_out, sl,
            hb[t & 1], hb[(t + 1) & 1], out, t);

    // final h after 128 steps lives in hb[0]
    tail_logits<<<dim3(8, 16), 256, 0, stream>>>(h0, W_out, b_out, out);
}